// Round 1
// baseline (619.023 us; speedup 1.0000x reference)
//
#include <hip/hip_runtime.h>
#include <cstddef>
#include <cstdint>

#define B_SZ    32768
#define NTAB    26
#define NROWS   200000
#define NPAIRS  351
#define RSTRIDE 416

// C[B, M] = relu(A[B, K (row-stride lda)] @ W[M, K]^T + bias), write with row-stride ldc
__global__ __launch_bounds__(256) void gemm_relu_k(
    const float* __restrict__ A, const float* __restrict__ W,
    const float* __restrict__ bias, float* __restrict__ C,
    int K, int lda, int M, int ldc)
{
    __shared__ float As[16][68];
    __shared__ float Ws[16][68];
    const int t = threadIdx.x;
    const int bBase = blockIdx.x << 6;
    const int mBase = blockIdx.y << 6;
    const int row0 = (t & 15) << 2;
    const int col0 = (t >> 4) << 2;
    float acc[4][4] = {};

    for (int kt = 0; kt < K; kt += 16) {
#pragma unroll
        for (int i = 0; i < 4; ++i) {
            const int e = t + (i << 8);
            const int r = e >> 4;
            const int k = e & 15;
            const int gk = kt + k;
            As[k][r] = (gk < K) ? A[(size_t)(bBase + r) * lda + gk] : 0.f;
            Ws[k][r] = (gk < K) ? W[(size_t)(mBase + r) * K + gk] : 0.f;
        }
        __syncthreads();
#pragma unroll
        for (int k = 0; k < 16; ++k) {
            const float4 a = *(const float4*)&As[k][row0];
            const float4 w = *(const float4*)&Ws[k][col0];
            acc[0][0] = fmaf(a.x, w.x, acc[0][0]);
            acc[0][1] = fmaf(a.x, w.y, acc[0][1]);
            acc[0][2] = fmaf(a.x, w.z, acc[0][2]);
            acc[0][3] = fmaf(a.x, w.w, acc[0][3]);
            acc[1][0] = fmaf(a.y, w.x, acc[1][0]);
            acc[1][1] = fmaf(a.y, w.y, acc[1][1]);
            acc[1][2] = fmaf(a.y, w.z, acc[1][2]);
            acc[1][3] = fmaf(a.y, w.w, acc[1][3]);
            acc[2][0] = fmaf(a.z, w.x, acc[2][0]);
            acc[2][1] = fmaf(a.z, w.y, acc[2][1]);
            acc[2][2] = fmaf(a.z, w.z, acc[2][2]);
            acc[2][3] = fmaf(a.z, w.w, acc[2][3]);
            acc[3][0] = fmaf(a.w, w.x, acc[3][0]);
            acc[3][1] = fmaf(a.w, w.y, acc[3][1]);
            acc[3][2] = fmaf(a.w, w.z, acc[3][2]);
            acc[3][3] = fmaf(a.w, w.w, acc[3][3]);
        }
        __syncthreads();
    }

    const float4 bv = *(const float4*)&bias[mBase + col0];
#pragma unroll
    for (int i = 0; i < 4; ++i) {
        float4 o;
        o.x = fmaxf(acc[i][0] + bv.x, 0.f);
        o.y = fmaxf(acc[i][1] + bv.y, 0.f);
        o.z = fmaxf(acc[i][2] + bv.z, 0.f);
        o.w = fmaxf(acc[i][3] + bv.w, 0.f);
        *(float4*)&C[(size_t)(bBase + row0 + i) * ldc + mBase + col0] = o;
    }
}

// One block per sample: gather 26 embedding rows + x_bot (already in R[:, :64]),
// compute 351 strict-lower-triangular pairwise dot products into R[:, 64:415].
__global__ __launch_bounds__(128) void interact_k(
    const float* __restrict__ emb, const int* __restrict__ idx,
    float* __restrict__ R)
{
    const int b = blockIdx.x;
    const int t = threadIdx.x;
    __shared__ float T[27][68];
    const float* __restrict__ Rrow = R + (size_t)b * RSTRIDE;

    for (int i = t; i < 27 * 16; i += 128) {
        const int row = i >> 4;
        const int seg = i & 15;
        const float* src;
        if (row == 0) {
            src = Rrow + (seg << 2);   // x_bot lives in R[:, :64]
        } else {
            const int r = idx[(size_t)(row - 1) * B_SZ + b];
            src = emb + ((size_t)(row - 1) * NROWS + (size_t)r) * 64 + (seg << 2);
        }
        *(float4*)&T[row][seg << 2] = *(const float4*)src;
    }
    __syncthreads();

    float* __restrict__ Rout = R + (size_t)b * RSTRIDE + 64;
    for (int p = t; p < NPAIRS; p += 128) {
        // pair p -> (i, j), j < i, numpy tril_indices(k=-1) row-major order
        int i = (int)((1.f + sqrtf(1.f + 8.f * (float)p)) * 0.5f);
        while ((i * (i - 1)) / 2 > p) --i;
        while (((i + 1) * i) / 2 <= p) ++i;
        const int j = p - (i * (i - 1)) / 2;
        const float* ti = T[i];
        const float* tj = T[j];
        float s = 0.f;
#pragma unroll
        for (int k = 0; k < 16; ++k) {
            const float4 x = *(const float4*)&ti[k << 2];
            const float4 y = *(const float4*)&tj[k << 2];
            s = fmaf(x.x, y.x, s);
            s = fmaf(x.y, y.y, s);
            s = fmaf(x.z, y.z, s);
            s = fmaf(x.w, y.w, s);
        }
        Rout[p] = s;
    }
}

// p[b] = sigmoid(dot(h1[b, :256], tw2) + tb2) — one wave per sample
__global__ __launch_bounds__(256) void top2_k(
    const float* __restrict__ h, const float* __restrict__ w2,
    const float* __restrict__ b2, float* __restrict__ out)
{
    const int gid = blockIdx.x * 256 + threadIdx.x;
    const int wave = gid >> 6;
    const int lane = threadIdx.x & 63;
    const float4 x = *(const float4*)&h[(size_t)wave * 256 + (lane << 2)];
    const float4 w = *(const float4*)&w2[lane << 2];
    float s = x.x * w.x + x.y * w.y + x.z * w.z + x.w * w.w;
#pragma unroll
    for (int off = 32; off > 0; off >>= 1) s += __shfl_down(s, off, 64);
    if (lane == 0) out[wave] = 1.f / (1.f + expf(-(s + b2[0])));
}

extern "C" void kernel_launch(void* const* d_in, const int* in_sizes, int n_in,
                              void* d_out, int out_size, void* d_ws, size_t ws_size,
                              hipStream_t stream)
{
    (void)in_sizes; (void)n_in; (void)out_size; (void)ws_size;
    const float* dense_x = (const float*)d_in[0];
    const int*   indices = (const int*)d_in[1];
    const float* emb     = (const float*)d_in[2];
    const float* bw0 = (const float*)d_in[3];
    const float* bb0 = (const float*)d_in[4];
    const float* bw1 = (const float*)d_in[5];
    const float* bb1 = (const float*)d_in[6];
    const float* bw2 = (const float*)d_in[7];
    const float* bb2 = (const float*)d_in[8];
    const float* tw0 = (const float*)d_in[9];
    const float* tb0 = (const float*)d_in[10];
    const float* tw1 = (const float*)d_in[11];
    const float* tb1 = (const float*)d_in[12];
    const float* tw2 = (const float*)d_in[13];
    const float* tb2 = (const float*)d_in[14];
    float* out = (float*)d_out;

    float* buf512 = (float*)d_ws;                        // B x 512 (h0, th0)
    float* buf256 = buf512 + (size_t)B_SZ * 512;         // B x 256 (h1, th1)
    float* R      = buf256 + (size_t)B_SZ * 256;         // B x 416 (x_bot | Zflat)

    const dim3 blk(256);
    // bottom MLP: 13 -> 512 -> 256 -> 64 (x_bot written straight into R[:, :64])
    gemm_relu_k<<<dim3(B_SZ / 64, 8), blk, 0, stream>>>(dense_x, bw0, bb0, buf512, 13, 13, 512, 512);
    gemm_relu_k<<<dim3(B_SZ / 64, 4), blk, 0, stream>>>(buf512, bw1, bb1, buf256, 512, 512, 256, 256);
    gemm_relu_k<<<dim3(B_SZ / 64, 1), blk, 0, stream>>>(buf256, bw2, bb2, R, 256, 256, 64, RSTRIDE);
    // embedding gather + pairwise interactions
    interact_k<<<dim3(B_SZ), dim3(128), 0, stream>>>(emb, indices, R);
    // top MLP: 415 -> 512 -> 256 -> sigmoid
    gemm_relu_k<<<dim3(B_SZ / 64, 8), blk, 0, stream>>>(R, tw0, tb0, buf512, 415, RSTRIDE, 512, 512);
    gemm_relu_k<<<dim3(B_SZ / 64, 4), blk, 0, stream>>>(buf512, tw1, tb1, buf256, 512, 512, 256, 256);
    top2_k<<<dim3(B_SZ / 4), blk, 0, stream>>>(buf256, tw2, tb2, out);
}

// Round 2
// 179.295 us; speedup vs baseline: 3.4525x; 3.4525x over previous
//
#include <hip/hip_runtime.h>
#include <cstddef>
#include <cstdint>

#define B_SZ    32768
#define NTAB    26
#define NROWS   200000
#define NPAIRS  351
#define RSTRIDE 416

typedef __attribute__((ext_vector_type(8))) short short8v;
typedef __attribute__((ext_vector_type(4))) float f32x4;

__device__ __forceinline__ ushort f2bf(float f) {
    uint32_t u = __builtin_bit_cast(uint32_t, f);
    u += 0x7FFFu + ((u >> 16) & 1u);
    return (ushort)(u >> 16);
}
__device__ __forceinline__ float bf2f(ushort h) {
    uint32_t u = ((uint32_t)h) << 16;
    return __builtin_bit_cast(float, u);
}

// fp32 [rows][K] -> bf16 [rows][Kp], zero-pad k in [K, Kp)
__global__ __launch_bounds__(256) void convpad_k(
    const float* __restrict__ src, ushort* __restrict__ dst,
    int rows, int K, int Kp)
{
    int i = blockIdx.x * 256 + threadIdx.x;
    if (i >= rows * Kp) return;
    int r = i / Kp, k = i - r * Kp;
    dst[i] = (k < K) ? f2bf(src[(size_t)r * K + k]) : (ushort)0;
}

// C[B, M] = relu(A @ W^T + bias) in bf16. A: [B][lda] bf16, W: [M][K] bf16 row-major.
// BM=128 rows. 4 waves arranged WM x WN. K multiple of 32.
template<int BN, int WM, int WN>
__global__ __launch_bounds__(256) void gemm_mfma_k(
    const ushort* __restrict__ A, const ushort* __restrict__ W,
    const float* __restrict__ bias, ushort* __restrict__ C,
    int K, int lda, int ldc)
{
    constexpr int BM = 128;
    constexpr int MF = BM / (16 * WM);
    constexpr int NF = BN / (16 * WN);
    constexpr int LS = 40;            // 32 + 8 pad (80 B stride: 2-way alias = free)
    __shared__ __align__(16) ushort As[BM * LS];
    __shared__ __align__(16) ushort Ws[BN * LS];
    const int t = threadIdx.x;
    const int lane = t & 63;
    const int w = t >> 6;
    const int wr = w / WN;
    const int wc = w % WN;
    const int bBase = blockIdx.x * BM;
    const int mBase = blockIdx.y * BN;
    const int fr = lane & 15;
    const int kofs = (lane >> 4) * 8;

    f32x4 acc[MF][NF] = {};

    for (int kt = 0; kt < K; kt += 32) {
#pragma unroll
        for (int i = 0; i < (BM * 4) / 256; ++i) {
            int c = t + i * 256;
            int r = c >> 2, s = c & 3;
            *(short8v*)&As[r * LS + s * 8] =
                *(const short8v*)&A[(size_t)(bBase + r) * lda + kt + s * 8];
        }
#pragma unroll
        for (int i = 0; i < (BN * 4) / 256; ++i) {
            int c = t + i * 256;
            int r = c >> 2, s = c & 3;
            *(short8v*)&Ws[r * LS + s * 8] =
                *(const short8v*)&W[(size_t)(mBase + r) * K + kt + s * 8];
        }
        __syncthreads();
        short8v a[MF], b[NF];
#pragma unroll
        for (int m = 0; m < MF; ++m)
            a[m] = *(const short8v*)&As[(wr * MF * 16 + m * 16 + fr) * LS + kofs];
#pragma unroll
        for (int n = 0; n < NF; ++n)
            b[n] = *(const short8v*)&Ws[(wc * NF * 16 + n * 16 + fr) * LS + kofs];
#pragma unroll
        for (int m = 0; m < MF; ++m)
#pragma unroll
            for (int n = 0; n < NF; ++n)
                acc[m][n] = __builtin_amdgcn_mfma_f32_16x16x32_bf16(a[m], b[n], acc[m][n], 0, 0, 0);
        __syncthreads();
    }

    const int rbase = (lane >> 4) * 4;
#pragma unroll
    for (int n = 0; n < NF; ++n) {
        const int col = mBase + wc * NF * 16 + n * 16 + fr;
        const float bv = bias[col];
#pragma unroll
        for (int m = 0; m < MF; ++m) {
#pragma unroll
            for (int j = 0; j < 4; ++j) {
                const int row = bBase + wr * MF * 16 + m * 16 + rbase + j;
                C[(size_t)row * ldc + col] = f2bf(fmaxf(acc[m][n][j] + bv, 0.f));
            }
        }
    }
}

// One block per sample: gather 26 fp32 embedding rows + bf16 x_bot (R[:, :64]),
// 351 pairwise fp32 dots -> bf16 into R[:, 64:415]; zero R[:, 415].
__global__ __launch_bounds__(128) void interact_k(
    const float* __restrict__ emb, const int* __restrict__ idx,
    ushort* __restrict__ R)
{
    const int b = blockIdx.x;
    const int t = threadIdx.x;
    __shared__ float T[27][68];
    __shared__ int sidx[26];
    ushort* __restrict__ Rrow = R + (size_t)b * RSTRIDE;

    if (t < 26) sidx[t] = idx[(size_t)t * B_SZ + b];
    if (t < 64) T[0][t] = bf2f(Rrow[t]);
    __syncthreads();

    for (int i = t; i < 26 * 16; i += 128) {
        const int row = i >> 4, seg = i & 15;
        const float* src = emb + ((size_t)row * NROWS + (size_t)sidx[row]) * 64 + (seg << 2);
        *(float4*)&T[row + 1][seg << 2] = *(const float4*)src;
    }
    __syncthreads();

    for (int p = t; p < 352; p += 128) {
        if (p == 351) { Rrow[64 + 351] = 0; continue; }
        int i = (int)((1.f + sqrtf(1.f + 8.f * (float)p)) * 0.5f);
        while ((i * (i - 1)) / 2 > p) --i;
        while (((i + 1) * i) / 2 <= p) ++i;
        const int j = p - (i * (i - 1)) / 2;
        const float* ti = T[i];
        const float* tj = T[j];
        float s = 0.f;
#pragma unroll
        for (int k = 0; k < 16; ++k) {
            const float4 x = *(const float4*)&ti[k << 2];
            const float4 y = *(const float4*)&tj[k << 2];
            s = fmaf(x.x, y.x, s);
            s = fmaf(x.y, y.y, s);
            s = fmaf(x.z, y.z, s);
            s = fmaf(x.w, y.w, s);
        }
        Rrow[64 + p] = f2bf(s);
    }
}

// p[b] = sigmoid(dot(h1[b, :256] (bf16), tw2) + tb2) — one wave per sample
__global__ __launch_bounds__(256) void top2_k(
    const ushort* __restrict__ h, const float* __restrict__ w2,
    const float* __restrict__ b2, float* __restrict__ out)
{
    const int gid = blockIdx.x * 256 + threadIdx.x;
    const int wave = gid >> 6;
    const int lane = threadIdx.x & 63;
    const ushort4 x = *(const ushort4*)&h[(size_t)wave * 256 + (lane << 2)];
    const float4 wv = *(const float4*)&w2[lane << 2];
    float s = bf2f(x.x) * wv.x + bf2f(x.y) * wv.y + bf2f(x.z) * wv.z + bf2f(x.w) * wv.w;
#pragma unroll
    for (int off = 32; off > 0; off >>= 1) s += __shfl_down(s, off, 64);
    if (lane == 0) out[wave] = 1.f / (1.f + expf(-(s + b2[0])));
}

extern "C" void kernel_launch(void* const* d_in, const int* in_sizes, int n_in,
                              void* d_out, int out_size, void* d_ws, size_t ws_size,
                              hipStream_t stream)
{
    (void)in_sizes; (void)n_in; (void)out_size; (void)ws_size;
    const float* dense_x = (const float*)d_in[0];
    const int*   indices = (const int*)d_in[1];
    const float* emb     = (const float*)d_in[2];
    const float* bw0 = (const float*)d_in[3];
    const float* bb0 = (const float*)d_in[4];
    const float* bw1 = (const float*)d_in[5];
    const float* bb1 = (const float*)d_in[6];
    const float* bw2 = (const float*)d_in[7];
    const float* bb2 = (const float*)d_in[8];
    const float* tw0 = (const float*)d_in[9];
    const float* tb0 = (const float*)d_in[10];
    const float* tw1 = (const float*)d_in[11];
    const float* tb1 = (const float*)d_in[12];
    const float* tw2 = (const float*)d_in[13];
    const float* tb2 = (const float*)d_in[14];
    float* out = (float*)d_out;

    // workspace layout (ushort units, all offsets 256B-aligned)
    ushort* ws16      = (ushort*)d_ws;
    ushort* dense_pad = ws16;                      // B x 32
    ushort* h0        = dense_pad + (size_t)B_SZ * 32;    // B x 512 (h0 / th0)
    ushort* h1        = h0 + (size_t)B_SZ * 512;          // B x 256 (h1 / th1)
    ushort* Rb        = h1 + (size_t)B_SZ * 256;          // B x 416
    ushort* bw0p      = Rb + (size_t)B_SZ * RSTRIDE;      // 512 x 32
    ushort* tw0p      = bw0p + 512 * 32;                  // 512 x 416
    ushort* bw1c      = tw0p + 512 * 416;                 // 256 x 512
    ushort* bw2c      = bw1c + 256 * 512;                 // 64 x 256
    ushort* tw1c      = bw2c + 64 * 256;                  // 256 x 512

    const dim3 blk(256);
    // weight / input conversions to bf16 (pad K to multiple of 32 where needed)
    convpad_k<<<dim3((B_SZ * 32) / 256), blk, 0, stream>>>(dense_x, dense_pad, B_SZ, 13, 32);
    convpad_k<<<dim3((512 * 32) / 256), blk, 0, stream>>>(bw0, bw0p, 512, 13, 32);
    convpad_k<<<dim3((512 * 416) / 256), blk, 0, stream>>>(tw0, tw0p, 512, 415, 416);
    convpad_k<<<dim3((256 * 512) / 256), blk, 0, stream>>>(bw1, bw1c, 256, 512, 512);
    convpad_k<<<dim3((64 * 256) / 256), blk, 0, stream>>>(bw2, bw2c, 64, 256, 256);
    convpad_k<<<dim3((256 * 512) / 256), blk, 0, stream>>>(tw1, tw1c, 256, 512, 512);

    // bottom MLP: 13(->32) -> 512 -> 256 -> 64 (x_bot straight into R[:, :64])
    gemm_mfma_k<128, 2, 2><<<dim3(B_SZ / 128, 4), blk, 0, stream>>>(dense_pad, bw0p, bb0, h0, 32, 32, 512);
    gemm_mfma_k<128, 2, 2><<<dim3(B_SZ / 128, 2), blk, 0, stream>>>(h0, bw1c, bb1, h1, 512, 512, 256);
    gemm_mfma_k<64, 4, 1><<<dim3(B_SZ / 128, 1), blk, 0, stream>>>(h1, bw2c, bb2, Rb, 256, 256, RSTRIDE);
    // embedding gather + pairwise interactions
    interact_k<<<dim3(B_SZ), dim3(128), 0, stream>>>(emb, indices, Rb);
    // top MLP: 415(->416) -> 512 -> 256 -> sigmoid
    gemm_mfma_k<128, 2, 2><<<dim3(B_SZ / 128, 4), blk, 0, stream>>>(Rb, tw0p, tb0, h0, 416, RSTRIDE, 512);
    gemm_mfma_k<128, 2, 2><<<dim3(B_SZ / 128, 2), blk, 0, stream>>>(h0, tw1c, tb1, h1, 512, 512, 256);
    top2_k<<<dim3(B_SZ / 4), blk, 0, stream>>>(h1, tw2, tb2, out);
}

// Round 3
// 172.798 us; speedup vs baseline: 3.5824x; 1.0376x over previous
//
#include <hip/hip_runtime.h>
#include <cstddef>
#include <cstdint>

#define B_SZ    32768
#define NTAB    26
#define NROWS   200000
#define RSTRIDE 416

typedef __attribute__((ext_vector_type(8))) short short8v;
typedef __attribute__((ext_vector_type(4))) float f32x4;

__device__ __forceinline__ ushort f2bf(float f) {
    uint32_t u = __builtin_bit_cast(uint32_t, f);
    u += 0x7FFFu + ((u >> 16) & 1u);
    return (ushort)(u >> 16);
}
__device__ __forceinline__ float bf2f(ushort h) {
    uint32_t u = ((uint32_t)h) << 16;
    return __builtin_bit_cast(float, u);
}

// All fp32->bf16 conversions (with K->Kp zero pad) in ONE kernel.
// Flat ranges: dense 1048576 | bw0 16384 | tw0 212992 | bw1 131072 | bw2 16384 | tw1 131072
__global__ __launch_bounds__(256) void conv_all_k(
    const float* __restrict__ dense_x, const float* __restrict__ bw0,
    const float* __restrict__ tw0, const float* __restrict__ bw1,
    const float* __restrict__ bw2, const float* __restrict__ tw1,
    ushort* __restrict__ dense_pad, ushort* __restrict__ bw0p,
    ushort* __restrict__ tw0p, ushort* __restrict__ bw1c,
    ushort* __restrict__ bw2c, ushort* __restrict__ tw1c)
{
    const int gid = blockIdx.x * 256 + threadIdx.x;
    if (gid < 1048576) {
        int r = gid >> 5, k = gid & 31;
        dense_pad[gid] = (k < 13) ? f2bf(dense_x[r * 13 + k]) : (ushort)0;
    } else if (gid < 1064960) {
        int i = gid - 1048576; int r = i >> 5, k = i & 31;
        bw0p[i] = (k < 13) ? f2bf(bw0[r * 13 + k]) : (ushort)0;
    } else if (gid < 1277952) {
        int i = gid - 1064960; int r = i / 416, k = i - r * 416;
        tw0p[i] = (k < 415) ? f2bf(tw0[r * 415 + k]) : (ushort)0;
    } else if (gid < 1409024) {
        int i = gid - 1277952; bw1c[i] = f2bf(bw1[i]);
    } else if (gid < 1425408) {
        int i = gid - 1409024; bw2c[i] = f2bf(bw2[i]);
    } else if (gid < 1556480) {
        int i = gid - 1425408; tw1c[i] = f2bf(tw1[i]);
    }
}

// C[B, M] = relu(A @ W^T + bias), bf16 in/out, fp32 accum.
// global_load_lds(16B) staging, linear LDS + XOR-swizzled source/read.
// Swapped-operand MFMA: D cols = samples (lane-local) -> vectorized ushort4 C-stores.
// FUSE: instead of storing C, compute sigmoid(relu(...) . w2 + b2) per sample (needs BN = full N, WM=1).
template<int BM, int BN, int WM, int WN, bool FUSE>
__global__ __launch_bounds__(256) void gemm_k(
    const ushort* __restrict__ A, const ushort* __restrict__ W,
    const float* __restrict__ bias, ushort* __restrict__ C,
    int K, int lda, int ldc,
    const float* __restrict__ w2, const float* __restrict__ b2,
    float* __restrict__ out)
{
    constexpr int MF = BM / (16 * WM);
    constexpr int NF = BN / (16 * WN);
    constexpr int AISS = (BM * 4) / 256;   // 16B units / 256 threads
    constexpr int WISS = (BN * 4) / 256;
    __shared__ __align__(16) ushort As[BM * 32];
    __shared__ __align__(16) ushort Ws[BN * 32];
    __shared__ float red[WM * WN][BM];     // FUSE reduction scratch

    const int t = threadIdx.x;
    const int lane = t & 63;
    const int w = t >> 6;
    const int wr = w / WN, wc = w % WN;
    const int bBase = blockIdx.x * BM;
    const int mBase = blockIdx.y * BN;
    const int fr = lane & 15;
    const int j16 = lane >> 4;

    f32x4 acc[MF][NF] = {};

    for (int kt = 0; kt < K; kt += 32) {
#pragma unroll
        for (int i = 0; i < AISS; ++i) {
            const int idx = i * 256 + t;
            const int r = idx >> 2, u = idx & 3;
            const int us = u ^ ((r >> 1) & 3);
            const ushort* g = A + (size_t)(bBase + r) * lda + kt + us * 8;
            __builtin_amdgcn_global_load_lds(
                (const __attribute__((address_space(1))) unsigned int*)g,
                (__attribute__((address_space(3))) unsigned int*)&As[idx * 8], 16, 0, 0);
        }
#pragma unroll
        for (int i = 0; i < WISS; ++i) {
            const int idx = i * 256 + t;
            const int r = idx >> 2, u = idx & 3;
            const int us = u ^ ((r >> 1) & 3);
            const ushort* g = W + (size_t)(mBase + r) * K + kt + us * 8;
            __builtin_amdgcn_global_load_lds(
                (const __attribute__((address_space(1))) unsigned int*)g,
                (__attribute__((address_space(3))) unsigned int*)&Ws[idx * 8], 16, 0, 0);
        }
        __syncthreads();
        short8v a[MF], b[NF];
#pragma unroll
        for (int m = 0; m < MF; ++m) {
            const int r = wr * MF * 16 + m * 16 + fr;
            a[m] = *(const short8v*)&As[r * 32 + (j16 ^ ((r >> 1) & 3)) * 8];
        }
#pragma unroll
        for (int n = 0; n < NF; ++n) {
            const int r = wc * NF * 16 + n * 16 + fr;
            b[n] = *(const short8v*)&Ws[r * 32 + (j16 ^ ((r >> 1) & 3)) * 8];
        }
#pragma unroll
        for (int m = 0; m < MF; ++m)
#pragma unroll
            for (int n = 0; n < NF; ++n)
                acc[m][n] = __builtin_amdgcn_mfma_f32_16x16x32_bf16(b[n], a[m], acc[m][n], 0, 0, 0);
        __syncthreads();
    }

    const int cb = j16 * 4;   // channel sub-base within a 16-block (D rows)
    if constexpr (FUSE) {
        // per-lane partial dot over this lane's channels, per sample m
        float part[MF];
#pragma unroll
        for (int m = 0; m < MF; ++m) part[m] = 0.f;
#pragma unroll
        for (int n = 0; n < NF; ++n) {
            const int ch = wc * NF * 16 + n * 16 + cb;
            const float4 bv = *(const float4*)&bias[ch];
            const float4 wv = *(const float4*)&w2[ch];
#pragma unroll
            for (int m = 0; m < MF; ++m) {
                part[m] += fmaxf(acc[m][n][0] + bv.x, 0.f) * wv.x
                         + fmaxf(acc[m][n][1] + bv.y, 0.f) * wv.y
                         + fmaxf(acc[m][n][2] + bv.z, 0.f) * wv.z
                         + fmaxf(acc[m][n][3] + bv.w, 0.f) * wv.w;
            }
        }
#pragma unroll
        for (int m = 0; m < MF; ++m) {
            float v = part[m];
            v += __shfl_xor(v, 16, 64);
            v += __shfl_xor(v, 32, 64);
            if (lane < 16) red[wc][m * 16 + fr] = v;
        }
        __syncthreads();
        if (t < BM) {
            float s = 0.f;
#pragma unroll
            for (int q = 0; q < WN; ++q) s += red[q][t];
            out[bBase + t] = 1.f / (1.f + expf(-(s + b2[0])));
        }
    } else {
#pragma unroll
        for (int n = 0; n < NF; ++n) {
            const int ch = mBase + wc * NF * 16 + n * 16 + cb;
            const float4 bv = *(const float4*)&bias[ch];
#pragma unroll
            for (int m = 0; m < MF; ++m) {
                const int row = bBase + wr * MF * 16 + m * 16 + fr;
                ushort4 o;
                o.x = f2bf(fmaxf(acc[m][n][0] + bv.x, 0.f));
                o.y = f2bf(fmaxf(acc[m][n][1] + bv.y, 0.f));
                o.z = f2bf(fmaxf(acc[m][n][2] + bv.z, 0.f));
                o.w = f2bf(fmaxf(acc[m][n][3] + bv.w, 0.f));
                *(ushort4*)&C[(size_t)row * ldc + ch] = o;
            }
        }
    }
}

// One block per sample: gather 26 fp32 embedding rows + bf16 x_bot (R[:, :64]),
// 351 pairwise fp32 dots -> bf16 into R[:, 64:415]; zero R[:, 415].
__global__ __launch_bounds__(128) void interact_k(
    const float* __restrict__ emb, const int* __restrict__ idx,
    ushort* __restrict__ R)
{
    const int b = blockIdx.x;
    const int t = threadIdx.x;
    __shared__ float T[27][68];
    __shared__ int sidx[26];
    ushort* __restrict__ Rrow = R + (size_t)b * RSTRIDE;

    if (t < 26) sidx[t] = idx[(size_t)t * B_SZ + b];
    if (t < 64) T[0][t] = bf2f(Rrow[t]);
    __syncthreads();

    for (int i = t; i < 26 * 16; i += 128) {
        const int row = i >> 4, seg = i & 15;
        const float* src = emb + ((size_t)row * NROWS + (size_t)sidx[row]) * 64 + (seg << 2);
        *(float4*)&T[row + 1][seg << 2] = *(const float4*)src;
    }
    __syncthreads();

    for (int p = t; p < 352; p += 128) {
        if (p == 351) { Rrow[64 + 351] = 0; continue; }
        int i = (int)((1.f + sqrtf(1.f + 8.f * (float)p)) * 0.5f);
        while ((i * (i - 1)) / 2 > p) --i;
        while (((i + 1) * i) / 2 <= p) ++i;
        const int j = p - (i * (i - 1)) / 2;
        const float* ti = T[i];
        const float* tj = T[j];
        float s = 0.f;
#pragma unroll
        for (int k = 0; k < 16; ++k) {
            const float4 x = *(const float4*)&ti[k << 2];
            const float4 y = *(const float4*)&tj[k << 2];
            s = fmaf(x.x, y.x, s);
            s = fmaf(x.y, y.y, s);
            s = fmaf(x.z, y.z, s);
            s = fmaf(x.w, y.w, s);
        }
        Rrow[64 + p] = f2bf(s);
    }
}

extern "C" void kernel_launch(void* const* d_in, const int* in_sizes, int n_in,
                              void* d_out, int out_size, void* d_ws, size_t ws_size,
                              hipStream_t stream)
{
    (void)in_sizes; (void)n_in; (void)out_size; (void)ws_size;
    const float* dense_x = (const float*)d_in[0];
    const int*   indices = (const int*)d_in[1];
    const float* emb     = (const float*)d_in[2];
    const float* bw0 = (const float*)d_in[3];
    const float* bb0 = (const float*)d_in[4];
    const float* bw1 = (const float*)d_in[5];
    const float* bb1 = (const float*)d_in[6];
    const float* bw2 = (const float*)d_in[7];
    const float* bb2 = (const float*)d_in[8];
    const float* tw0 = (const float*)d_in[9];
    const float* tb0 = (const float*)d_in[10];
    const float* tw1 = (const float*)d_in[11];
    const float* tb1 = (const float*)d_in[12];
    const float* tw2 = (const float*)d_in[13];
    const float* tb2 = (const float*)d_in[14];
    float* out = (float*)d_out;

    ushort* ws16      = (ushort*)d_ws;
    ushort* dense_pad = ws16;                              // B x 32
    ushort* h0        = dense_pad + (size_t)B_SZ * 32;     // B x 512 (h0 / th0)
    ushort* h1        = h0 + (size_t)B_SZ * 512;           // B x 256 (bottom h1)
    ushort* Rb        = h1 + (size_t)B_SZ * 256;           // B x 416
    ushort* bw0p      = Rb + (size_t)B_SZ * RSTRIDE;       // 512 x 32
    ushort* tw0p      = bw0p + 512 * 32;                   // 512 x 416
    ushort* bw1c      = tw0p + 512 * 416;                  // 256 x 512
    ushort* bw2c      = bw1c + 256 * 512;                  // 64 x 256
    ushort* tw1c      = bw2c + 64 * 256;                   // 256 x 512

    conv_all_k<<<dim3(6080), dim3(256), 0, stream>>>(
        dense_x, bw0, tw0, bw1, bw2, tw1,
        dense_pad, bw0p, tw0p, bw1c, bw2c, tw1c);

    // bottom MLP: 13(->32) -> 512 -> 256 -> 64 (x_bot straight into R[:, :64])
    gemm_k<128, 128, 2, 2, false><<<dim3(256, 4), dim3(256), 0, stream>>>(
        dense_pad, bw0p, bb0, h0, 32, 32, 512, nullptr, nullptr, nullptr);
    gemm_k<128, 128, 2, 2, false><<<dim3(256, 2), dim3(256), 0, stream>>>(
        h0, bw1c, bb1, h1, 512, 512, 256, nullptr, nullptr, nullptr);
    gemm_k<128, 64, 2, 2, false><<<dim3(256, 1), dim3(256), 0, stream>>>(
        h1, bw2c, bb2, Rb, 256, 256, RSTRIDE, nullptr, nullptr, nullptr);
    // embedding gather + pairwise interactions
    interact_k<<<dim3(B_SZ), dim3(128), 0, stream>>>(emb, indices, Rb);
    // top MLP: 415(->416) -> 512 -> 256 -> dot+sigmoid (fused)
    gemm_k<128, 128, 2, 2, false><<<dim3(256, 4), dim3(256), 0, stream>>>(
        Rb, tw0p, tb0, h0, 416, RSTRIDE, 512, nullptr, nullptr, nullptr);
    gemm_k<64, 256, 1, 4, true><<<dim3(512, 1), dim3(256), 0, stream>>>(
        h0, tw1c, tb1, nullptr, 512, 512, 0, tw2, tb2, out);
}

// Round 4
// 156.831 us; speedup vs baseline: 3.9471x; 1.1018x over previous
//
#include <hip/hip_runtime.h>
#include <cstddef>
#include <cstdint>

#define B_SZ    32768
#define NTAB    26
#define NROWS   200000
#define RSTRIDE 416

typedef __attribute__((ext_vector_type(8))) short short8v;
typedef __attribute__((ext_vector_type(4))) float f32x4;

__device__ __forceinline__ ushort f2bf(float f) {
    uint32_t u = __builtin_bit_cast(uint32_t, f);
    u += 0x7FFFu + ((u >> 16) & 1u);
    return (ushort)(u >> 16);
}
__device__ __forceinline__ float bf2f(ushort h) {
    uint32_t u = ((uint32_t)h) << 16;
    return __builtin_bit_cast(float, u);
}
__device__ __forceinline__ void stage16(const ushort* g, ushort* l) {
    __builtin_amdgcn_global_load_lds(
        (const __attribute__((address_space(1))) unsigned int*)g,
        (__attribute__((address_space(3))) unsigned int*)l, 16, 0, 0);
}

// All fp32->bf16 conversions (with K->Kp zero pad) in ONE kernel.
__global__ __launch_bounds__(256) void conv_all_k(
    const float* __restrict__ dense_x, const float* __restrict__ bw0,
    const float* __restrict__ tw0, const float* __restrict__ bw1,
    const float* __restrict__ bw2, const float* __restrict__ tw1,
    ushort* __restrict__ dense_pad, ushort* __restrict__ bw0p,
    ushort* __restrict__ tw0p, ushort* __restrict__ bw1c,
    ushort* __restrict__ bw2c, ushort* __restrict__ tw1c)
{
    const int gid = blockIdx.x * 256 + threadIdx.x;
    if (gid < 1048576) {
        int r = gid >> 5, k = gid & 31;
        dense_pad[gid] = (k < 13) ? f2bf(dense_x[r * 13 + k]) : (ushort)0;
    } else if (gid < 1064960) {
        int i = gid - 1048576; int r = i >> 5, k = i & 31;
        bw0p[i] = (k < 13) ? f2bf(bw0[r * 13 + k]) : (ushort)0;
    } else if (gid < 1277952) {
        int i = gid - 1064960; int r = i / 416, k = i - r * 416;
        tw0p[i] = (k < 415) ? f2bf(tw0[r * 415 + k]) : (ushort)0;
    } else if (gid < 1409024) {
        int i = gid - 1277952; bw1c[i] = f2bf(bw1[i]);
    } else if (gid < 1425408) {
        int i = gid - 1409024; bw2c[i] = f2bf(bw2[i]);
    } else if (gid < 1556480) {
        int i = gid - 1425408; tw1c[i] = f2bf(tw1[i]);
    }
}

// bot0: C[B, M] = relu(A @ W^T + bias), bf16, global_load_lds staging, swapped MFMA.
template<int BM, int BN, int WM, int WN>
__global__ __launch_bounds__(256) void gemm_k(
    const ushort* __restrict__ A, const ushort* __restrict__ W,
    const float* __restrict__ bias, ushort* __restrict__ C,
    int K, int lda, int ldc)
{
    constexpr int MF = BM / (16 * WM);
    constexpr int NF = BN / (16 * WN);
    constexpr int AISS = (BM * 4) / 256;
    constexpr int WISS = (BN * 4) / 256;
    __shared__ __align__(16) ushort As[BM * 32];
    __shared__ __align__(16) ushort Ws[BN * 32];
    const int t = threadIdx.x;
    const int lane = t & 63;
    const int w = t >> 6;
    const int wr = w / WN, wc = w % WN;
    const int bBase = blockIdx.x * BM;
    const int mBase = blockIdx.y * BN;
    const int fr = lane & 15;
    const int j16 = lane >> 4;

    f32x4 acc[MF][NF] = {};

    for (int kt = 0; kt < K; kt += 32) {
#pragma unroll
        for (int i = 0; i < AISS; ++i) {
            const int idx = i * 256 + t;
            const int r = idx >> 2, u = idx & 3;
            const int us = u ^ ((r >> 1) & 3);
            stage16(A + (size_t)(bBase + r) * lda + kt + us * 8, &As[idx * 8]);
        }
#pragma unroll
        for (int i = 0; i < WISS; ++i) {
            const int idx = i * 256 + t;
            const int r = idx >> 2, u = idx & 3;
            const int us = u ^ ((r >> 1) & 3);
            stage16(W + (size_t)(mBase + r) * K + kt + us * 8, &Ws[idx * 8]);
        }
        __syncthreads();
        short8v a[MF], b[NF];
#pragma unroll
        for (int m = 0; m < MF; ++m) {
            const int r = wr * MF * 16 + m * 16 + fr;
            a[m] = *(const short8v*)&As[r * 32 + (j16 ^ ((r >> 1) & 3)) * 8];
        }
#pragma unroll
        for (int n = 0; n < NF; ++n) {
            const int r = wc * NF * 16 + n * 16 + fr;
            b[n] = *(const short8v*)&Ws[r * 32 + (j16 ^ ((r >> 1) & 3)) * 8];
        }
#pragma unroll
        for (int m = 0; m < MF; ++m)
#pragma unroll
            for (int n = 0; n < NF; ++n)
                acc[m][n] = __builtin_amdgcn_mfma_f32_16x16x32_bf16(b[n], a[m], acc[m][n], 0, 0, 0);
        __syncthreads();
    }

    const int cb = j16 * 4;
#pragma unroll
    for (int n = 0; n < NF; ++n) {
        const int ch = mBase + wc * NF * 16 + n * 16 + cb;
        const float4 bv = *(const float4*)&bias[ch];
#pragma unroll
        for (int m = 0; m < MF; ++m) {
            const int row = bBase + wr * MF * 16 + m * 16 + fr;
            ushort4 o;
            o.x = f2bf(fmaxf(acc[m][n][0] + bv.x, 0.f));
            o.y = f2bf(fmaxf(acc[m][n][1] + bv.y, 0.f));
            o.z = f2bf(fmaxf(acc[m][n][2] + bv.z, 0.f));
            o.w = f2bf(fmaxf(acc[m][n][3] + bv.w, 0.f));
            *(ushort4*)&C[(size_t)row * ldc + ch] = o;
        }
    }
}

// Fused bot1+bot2: h1 = relu(h0 @ bw1^T + bb1) kept in LDS (bf16, XOR-swizzled),
// then x_bot = relu(h1 @ bw2^T + bb2) -> Rb[:, :64].  64 samples/block, 4 waves.
__global__ __launch_bounds__(256) void bot12_k(
    const ushort* __restrict__ h0, const ushort* __restrict__ bw1c,
    const float* __restrict__ bb1, const ushort* __restrict__ bw2c,
    const float* __restrict__ bb2, ushort* __restrict__ Rb)
{
    __shared__ __align__(16) ushort Ast[64 * 32];     // 4 KB
    __shared__ __align__(16) ushort Wst[256 * 32];    // 16 KB
    __shared__ __align__(16) ushort h1s[64 * 256];    // 32 KB
    const int t = threadIdx.x;
    const int lane = t & 63, w = t >> 6;              // 4 waves, WM=1 x WN=4
    const int fr = lane & 15, j16 = lane >> 4;
    const int bBase = blockIdx.x * 64;

    // phase A: h1 = relu(h0 @ bw1^T + bb1), K=512, N=256 (per wave N=64)
    f32x4 acc[4][4] = {};
    for (int kt = 0; kt < 512; kt += 32) {
        {
            const int r = t >> 2, u = t & 3, us = u ^ ((r >> 1) & 3);
            stage16(h0 + (size_t)(bBase + r) * 512 + kt + us * 8, &Ast[t * 8]);
        }
#pragma unroll
        for (int i = 0; i < 4; ++i) {
            const int idx = i * 256 + t;
            const int r = idx >> 2, u = idx & 3, us = u ^ ((r >> 1) & 3);
            stage16(bw1c + (size_t)r * 512 + kt + us * 8, &Wst[idx * 8]);
        }
        __syncthreads();
        short8v a[4], b[4];
#pragma unroll
        for (int m = 0; m < 4; ++m) {
            const int r = m * 16 + fr;
            a[m] = *(const short8v*)&Ast[r * 32 + (j16 ^ ((r >> 1) & 3)) * 8];
        }
#pragma unroll
        for (int n = 0; n < 4; ++n) {
            const int r = w * 64 + n * 16 + fr;
            b[n] = *(const short8v*)&Wst[r * 32 + (j16 ^ ((r >> 1) & 3)) * 8];
        }
#pragma unroll
        for (int m = 0; m < 4; ++m)
#pragma unroll
            for (int n = 0; n < 4; ++n)
                acc[m][n] = __builtin_amdgcn_mfma_f32_16x16x32_bf16(b[n], a[m], acc[m][n], 0, 0, 0);
        __syncthreads();
    }
    // epilogue: h1s[sample][ch], 16B-unit XOR swizzle by (sample&7)
#pragma unroll
    for (int n = 0; n < 4; ++n) {
        const int ch = w * 64 + n * 16 + j16 * 4;
        const float4 bv = *(const float4*)&bb1[ch];
#pragma unroll
        for (int m = 0; m < 4; ++m) {
            const int s = m * 16 + fr;
            ushort4 o;
            o.x = f2bf(fmaxf(acc[m][n][0] + bv.x, 0.f));
            o.y = f2bf(fmaxf(acc[m][n][1] + bv.y, 0.f));
            o.z = f2bf(fmaxf(acc[m][n][2] + bv.z, 0.f));
            o.w = f2bf(fmaxf(acc[m][n][3] + bv.w, 0.f));
            const int u = ch >> 3, su = u ^ (s & 7);
            *(ushort4*)&h1s[s * 256 + su * 8 + (ch & 7)] = o;
        }
    }
    __syncthreads();

    // phase B: x_bot = relu(h1 @ bw2^T + bb2), K=256, N=64 (per wave N=16)
    f32x4 acc2[4] = {};
    for (int kt = 0; kt < 256; kt += 32) {
        {
            const int r = t >> 2, u = t & 3, us = u ^ ((r >> 1) & 3);
            stage16(bw2c + (size_t)r * 256 + kt + us * 8, &Ast[t * 8]);
        }
        __syncthreads();
        short8v a2[4], b2;
#pragma unroll
        for (int m = 0; m < 4; ++m) {
            const int s = m * 16 + fr;
            const int u = (kt >> 3) + j16, su = u ^ (s & 7);
            a2[m] = *(const short8v*)&h1s[s * 256 + su * 8];
        }
        {
            const int r = w * 16 + fr;
            b2 = *(const short8v*)&Ast[r * 32 + (j16 ^ ((r >> 1) & 3)) * 8];
        }
#pragma unroll
        for (int m = 0; m < 4; ++m)
            acc2[m] = __builtin_amdgcn_mfma_f32_16x16x32_bf16(b2, a2[m], acc2[m], 0, 0, 0);
        __syncthreads();
    }
    {
        const int ch = w * 16 + j16 * 4;
        const float4 bv = *(const float4*)&bb2[ch];
#pragma unroll
        for (int m = 0; m < 4; ++m) {
            const int s = m * 16 + fr;
            ushort4 o;
            o.x = f2bf(fmaxf(acc2[m][0] + bv.x, 0.f));
            o.y = f2bf(fmaxf(acc2[m][1] + bv.y, 0.f));
            o.z = f2bf(fmaxf(acc2[m][2] + bv.z, 0.f));
            o.w = f2bf(fmaxf(acc2[m][3] + bv.w, 0.f));
            *(ushort4*)&Rb[(size_t)(bBase + s) * RSTRIDE + ch] = o;
        }
    }
}

// Fused top0+top1+top2: th0 = relu(R@tw0^T) -> LDS; th1 = relu(th0@tw1^T) in acc;
// out = sigmoid(th1 . tw2 + tb2).  64 samples/block, 512 threads (8 waves, 2x4).
__global__ __launch_bounds__(512) void top_k(
    const ushort* __restrict__ Rb, const ushort* __restrict__ tw0p,
    const float* __restrict__ tb0, const ushort* __restrict__ tw1c,
    const float* __restrict__ tb1, const float* __restrict__ tw2,
    const float* __restrict__ tb2, float* __restrict__ out)
{
    __shared__ __align__(16) ushort Ast[64 * 32];      // 4 KB
    __shared__ __align__(16) ushort Wst[512 * 32];     // 32 KB
    __shared__ __align__(16) ushort th0s[64 * 512];    // 64 KB
    __shared__ float red[4][64];
    const int t = threadIdx.x;
    const int lane = t & 63, w = t >> 6;
    const int wr = w >> 2, wc = w & 3;                 // 2 x 4 waves
    const int fr = lane & 15, j16 = lane >> 4;
    const int bBase = blockIdx.x * 64;

    // phase A: th0 = relu(R @ tw0^T + tb0), K=416, N=512 (per wave 32 samp x 128 ch)
    f32x4 acc[2][8] = {};
    for (int kt = 0; kt < 416; kt += 32) {
        if (t < 256) {
            const int r = t >> 2, u = t & 3, us = u ^ ((r >> 1) & 3);
            stage16(Rb + (size_t)(bBase + r) * RSTRIDE + kt + us * 8, &Ast[t * 8]);
        }
#pragma unroll
        for (int i = 0; i < 4; ++i) {
            const int idx = i * 512 + t;
            const int r = idx >> 2, u = idx & 3, us = u ^ ((r >> 1) & 3);
            stage16(tw0p + (size_t)r * RSTRIDE + kt + us * 8, &Wst[idx * 8]);
        }
        __syncthreads();
        short8v a[2], b[8];
#pragma unroll
        for (int m = 0; m < 2; ++m) {
            const int r = wr * 32 + m * 16 + fr;
            a[m] = *(const short8v*)&Ast[r * 32 + (j16 ^ ((r >> 1) & 3)) * 8];
        }
#pragma unroll
        for (int n = 0; n < 8; ++n) {
            const int r = wc * 128 + n * 16 + fr;
            b[n] = *(const short8v*)&Wst[r * 32 + (j16 ^ ((r >> 1) & 3)) * 8];
        }
#pragma unroll
        for (int m = 0; m < 2; ++m)
#pragma unroll
            for (int n = 0; n < 8; ++n)
                acc[m][n] = __builtin_amdgcn_mfma_f32_16x16x32_bf16(b[n], a[m], acc[m][n], 0, 0, 0);
        __syncthreads();
    }
    // epilogue -> th0s (row stride 512 ushorts = 64 units), swizzle by (s&7)
#pragma unroll
    for (int n = 0; n < 8; ++n) {
        const int ch = wc * 128 + n * 16 + j16 * 4;
        const float4 bv = *(const float4*)&tb0[ch];
#pragma unroll
        for (int m = 0; m < 2; ++m) {
            const int s = wr * 32 + m * 16 + fr;
            ushort4 o;
            o.x = f2bf(fmaxf(acc[m][n][0] + bv.x, 0.f));
            o.y = f2bf(fmaxf(acc[m][n][1] + bv.y, 0.f));
            o.z = f2bf(fmaxf(acc[m][n][2] + bv.z, 0.f));
            o.w = f2bf(fmaxf(acc[m][n][3] + bv.w, 0.f));
            const int u = ch >> 3, su = u ^ (s & 7);
            *(ushort4*)&th0s[s * 512 + su * 8 + (ch & 7)] = o;
        }
    }
    __syncthreads();

    // phase B: th1 = relu(th0 @ tw1^T + tb1), K=512, N=256 (per wave 32 samp x 64 ch)
    f32x4 acc2[2][4] = {};
    for (int kt = 0; kt < 512; kt += 32) {
#pragma unroll
        for (int i = 0; i < 2; ++i) {
            const int idx = i * 512 + t;
            const int r = idx >> 2, u = idx & 3, us = u ^ ((r >> 1) & 3);
            stage16(tw1c + (size_t)r * 512 + kt + us * 8, &Wst[idx * 8]);
        }
        __syncthreads();
        short8v a2[2], b2[4];
#pragma unroll
        for (int m = 0; m < 2; ++m) {
            const int s = wr * 32 + m * 16 + fr;
            const int u = (kt >> 3) + j16, su = u ^ (s & 7);
            a2[m] = *(const short8v*)&th0s[s * 512 + su * 8];
        }
#pragma unroll
        for (int n = 0; n < 4; ++n) {
            const int r = wc * 64 + n * 16 + fr;
            b2[n] = *(const short8v*)&Wst[r * 32 + (j16 ^ ((r >> 1) & 3)) * 8];
        }
#pragma unroll
        for (int m = 0; m < 2; ++m)
#pragma unroll
            for (int n = 0; n < 4; ++n)
                acc2[m][n] = __builtin_amdgcn_mfma_f32_16x16x32_bf16(b2[n], a2[m], acc2[m][n], 0, 0, 0);
        __syncthreads();
    }

    // phase C: out = sigmoid( relu(acc2 + tb1) . tw2 + tb2 )
    float part[2] = {0.f, 0.f};
#pragma unroll
    for (int n = 0; n < 4; ++n) {
        const int ch = wc * 64 + n * 16 + j16 * 4;
        const float4 bv = *(const float4*)&tb1[ch];
        const float4 wv = *(const float4*)&tw2[ch];
#pragma unroll
        for (int m = 0; m < 2; ++m) {
            part[m] += fmaxf(acc2[m][n][0] + bv.x, 0.f) * wv.x
                     + fmaxf(acc2[m][n][1] + bv.y, 0.f) * wv.y
                     + fmaxf(acc2[m][n][2] + bv.z, 0.f) * wv.z
                     + fmaxf(acc2[m][n][3] + bv.w, 0.f) * wv.w;
        }
    }
#pragma unroll
    for (int m = 0; m < 2; ++m) {
        float v = part[m];
        v += __shfl_xor(v, 16, 64);
        v += __shfl_xor(v, 32, 64);
        if (lane < 16) red[wc][wr * 32 + m * 16 + fr] = v;
    }
    __syncthreads();
    if (t < 64) {
        const float s = red[0][t] + red[1][t] + red[2][t] + red[3][t];
        out[bBase + t] = 1.f / (1.f + expf(-(s + tb2[0])));
    }
}

// One block per sample: gather 26 fp32 embedding rows + bf16 x_bot (R[:, :64]),
// 351 pairwise fp32 dots -> bf16 into R[:, 64:415]; zero R[:, 415].
__global__ __launch_bounds__(128) void interact_k(
    const float* __restrict__ emb, const int* __restrict__ idx,
    ushort* __restrict__ R)
{
    const int b = blockIdx.x;
    const int t = threadIdx.x;
    __shared__ float T[27][68];
    __shared__ int sidx[26];
    ushort* __restrict__ Rrow = R + (size_t)b * RSTRIDE;

    if (t < 26) sidx[t] = idx[(size_t)t * B_SZ + b];
    if (t < 64) T[0][t] = bf2f(Rrow[t]);
    __syncthreads();

    for (int i = t; i < 26 * 16; i += 128) {
        const int row = i >> 4, seg = i & 15;
        const float* src = emb + ((size_t)row * NROWS + (size_t)sidx[row]) * 64 + (seg << 2);
        *(float4*)&T[row + 1][seg << 2] = *(const float4*)src;
    }
    __syncthreads();

    for (int p = t; p < 352; p += 128) {
        if (p == 351) { Rrow[64 + 351] = 0; continue; }
        int i = (int)((1.f + sqrtf(1.f + 8.f * (float)p)) * 0.5f);
        while ((i * (i - 1)) / 2 > p) --i;
        while (((i + 1) * i) / 2 <= p) ++i;
        const int j = p - (i * (i - 1)) / 2;
        const float* ti = T[i];
        const float* tj = T[j];
        float s = 0.f;
#pragma unroll
        for (int k = 0; k < 16; ++k) {
            const float4 x = *(const float4*)&ti[k << 2];
            const float4 y = *(const float4*)&tj[k << 2];
            s = fmaf(x.x, y.x, s);
            s = fmaf(x.y, y.y, s);
            s = fmaf(x.z, y.z, s);
            s = fmaf(x.w, y.w, s);
        }
        Rrow[64 + p] = f2bf(s);
    }
}

extern "C" void kernel_launch(void* const* d_in, const int* in_sizes, int n_in,
                              void* d_out, int out_size, void* d_ws, size_t ws_size,
                              hipStream_t stream)
{
    (void)in_sizes; (void)n_in; (void)out_size; (void)ws_size;
    const float* dense_x = (const float*)d_in[0];
    const int*   indices = (const int*)d_in[1];
    const float* emb     = (const float*)d_in[2];
    const float* bw0 = (const float*)d_in[3];
    const float* bb0 = (const float*)d_in[4];
    const float* bw1 = (const float*)d_in[5];
    const float* bb1 = (const float*)d_in[6];
    const float* bw2 = (const float*)d_in[7];
    const float* bb2 = (const float*)d_in[8];
    const float* tw0 = (const float*)d_in[9];
    const float* tb0 = (const float*)d_in[10];
    const float* tw1 = (const float*)d_in[11];
    const float* tb1 = (const float*)d_in[12];
    const float* tw2 = (const float*)d_in[13];
    const float* tb2 = (const float*)d_in[14];
    float* out = (float*)d_out;

    ushort* ws16      = (ushort*)d_ws;
    ushort* dense_pad = ws16;                              // B x 32
    ushort* h0        = dense_pad + (size_t)B_SZ * 32;     // B x 512
    ushort* Rb        = h0 + (size_t)B_SZ * 512;           // B x 416
    ushort* bw0p      = Rb + (size_t)B_SZ * RSTRIDE;       // 512 x 32
    ushort* tw0p      = bw0p + 512 * 32;                   // 512 x 416
    ushort* bw1c      = tw0p + 512 * 416;                  // 256 x 512
    ushort* bw2c      = bw1c + 256 * 512;                  // 64 x 256
    ushort* tw1c      = bw2c + 64 * 256;                   // 256 x 512

    conv_all_k<<<dim3(6080), dim3(256), 0, stream>>>(
        dense_x, bw0, tw0, bw1, bw2, tw1,
        dense_pad, bw0p, tw0p, bw1c, bw2c, tw1c);

    // bot0: 13(->32) -> 512
    gemm_k<128, 128, 2, 2><<<dim3(256, 4), dim3(256), 0, stream>>>(
        dense_pad, bw0p, bb0, h0, 32, 32, 512);
    // fused bot1+bot2 -> x_bot into R[:, :64]
    bot12_k<<<dim3(512), dim3(256), 0, stream>>>(h0, bw1c, bb1, bw2c, bb2, Rb);
    // embedding gather + pairwise interactions
    interact_k<<<dim3(B_SZ), dim3(128), 0, stream>>>(emb, indices, Rb);
    // fused top MLP
    top_k<<<dim3(512), dim3(512), 0, stream>>>(Rb, tw0p, tb0, tw1c, tb1, tw2, tb2, out);
}

// Round 6
// 126.236 us; speedup vs baseline: 4.9037x; 1.2424x over previous
//
#include <hip/hip_runtime.h>
#include <cstddef>
#include <cstdint>

#define B_SZ    32768
#define NTAB    26
#define NROWS   200000

typedef __attribute__((ext_vector_type(8))) short short8v;
typedef __attribute__((ext_vector_type(4))) float f32x4;
typedef __attribute__((ext_vector_type(16))) float f32x16;

__device__ __forceinline__ ushort f2bf(float f) {
    uint32_t u = __builtin_bit_cast(uint32_t, f);
    u += 0x7FFFu + ((u >> 16) & 1u);
    return (ushort)(u >> 16);
}
__device__ __forceinline__ float bf2f(ushort h) {
    uint32_t u = ((uint32_t)h) << 16;
    return __builtin_bit_cast(float, u);
}
__device__ __forceinline__ void stage16(const ushort* g, ushort* l) {
    __builtin_amdgcn_global_load_lds(
        (const __attribute__((address_space(1))) unsigned int*)g,
        (__attribute__((address_space(3))) unsigned int*)l, 16, 0, 0);
}

// All fp32->bf16 conversions (with K->Kp zero pad) in ONE kernel.
__global__ __launch_bounds__(256) void conv_all_k(
    const float* __restrict__ dense_x, const float* __restrict__ bw0,
    const float* __restrict__ tw0, const float* __restrict__ bw1,
    const float* __restrict__ bw2, const float* __restrict__ tw1,
    ushort* __restrict__ dense_pad, ushort* __restrict__ bw0p,
    ushort* __restrict__ tw0p, ushort* __restrict__ bw1c,
    ushort* __restrict__ bw2c, ushort* __restrict__ tw1c)
{
    const int gid = blockIdx.x * 256 + threadIdx.x;
    if (gid < 1048576) {
        int r = gid >> 5, k = gid & 31;
        dense_pad[gid] = (k < 13) ? f2bf(dense_x[r * 13 + k]) : (ushort)0;
    } else if (gid < 1064960) {
        int i = gid - 1048576; int r = i >> 5, k = i & 31;
        bw0p[i] = (k < 13) ? f2bf(bw0[r * 13 + k]) : (ushort)0;
    } else if (gid < 1277952) {
        int i = gid - 1064960; int r = i / 416, k = i - r * 416;
        tw0p[i] = (k < 415) ? f2bf(tw0[r * 415 + k]) : (ushort)0;
    } else if (gid < 1409024) {
        int i = gid - 1277952; bw1c[i] = f2bf(bw1[i]);
    } else if (gid < 1425408) {
        int i = gid - 1409024; bw2c[i] = f2bf(bw2[i]);
    } else if (gid < 1556480) {
        int i = gid - 1425408; tw1c[i] = f2bf(tw1[i]);
    }
}

// ---------------------------------------------------------------------------
// Fused bottom MLP: 13(->32) -> 512 -> 256 -> 64. h0/h1 live only in LDS.
// 32 samples/block, 4 waves, LDS 64 KB -> 2 blocks/CU.
// ---------------------------------------------------------------------------
__global__ __launch_bounds__(256, 2) void bot012_k(
    const ushort* __restrict__ dense_pad, const ushort* __restrict__ bw0p,
    const float* __restrict__ bb0, const ushort* __restrict__ bw1c,
    const float* __restrict__ bb1, const ushort* __restrict__ bw2c,
    const float* __restrict__ bb2, ushort* __restrict__ Rb)
{
    __shared__ __align__(16) ushort h0s[32 * 512];   // 32 KB
    __shared__ __align__(16) ushort Wst[256 * 32];   // 16 KB staging
    __shared__ __align__(16) ushort h1s[32 * 256];   // 16 KB (dense tile overlays at P0)
    const int t = threadIdx.x;
    const int lane = t & 63, w = t >> 6;
    const int fr = lane & 15, j16 = lane >> 4;
    const int bBase = blockIdx.x * 32;

    // stage dense tile (32x32) into h1s region
    if (t < 128) {
        const int r = t >> 2, u = t & 3, us = u ^ ((r >> 1) & 3);
        stage16(dense_pad + (size_t)(bBase + r) * 32 + us * 8, &h1s[t * 8]);
    }

    // P0: h0 = relu(dense @ bw0^T + bb0), K=32, 2 channel halves of 256
    f32x4 acc0[2][2][4] = {};
#pragma unroll
    for (int hh = 0; hh < 2; ++hh) {
#pragma unroll
        for (int i = 0; i < 4; ++i) {
            const int idx = i * 256 + t;
            const int r = idx >> 2, u = idx & 3, us = u ^ ((r >> 1) & 3);
            stage16(bw0p + (size_t)(hh * 256 + r) * 32 + us * 8, &Wst[idx * 8]);
        }
        __syncthreads();
        short8v a[2], b[4];
#pragma unroll
        for (int m = 0; m < 2; ++m) {
            const int r = m * 16 + fr;
            a[m] = *(const short8v*)&h1s[r * 32 + (j16 ^ ((r >> 1) & 3)) * 8];
        }
#pragma unroll
        for (int n = 0; n < 4; ++n) {
            const int lr = w * 64 + n * 16 + fr;
            b[n] = *(const short8v*)&Wst[lr * 32 + (j16 ^ ((lr >> 1) & 3)) * 8];
        }
        __builtin_amdgcn_s_setprio(1);
#pragma unroll
        for (int m = 0; m < 2; ++m)
#pragma unroll
            for (int n = 0; n < 4; ++n)
                acc0[hh][m][n] = __builtin_amdgcn_mfma_f32_16x16x32_bf16(b[n], a[m], acc0[hh][m][n], 0, 0, 0);
        __builtin_amdgcn_s_setprio(0);
        __syncthreads();
    }
#pragma unroll
    for (int hh = 0; hh < 2; ++hh)
#pragma unroll
    for (int n = 0; n < 4; ++n) {
        const int ch = hh * 256 + w * 64 + n * 16 + j16 * 4;
        const float4 bv = *(const float4*)&bb0[ch];
#pragma unroll
        for (int m = 0; m < 2; ++m) {
            const int s = m * 16 + fr;
            ushort4 o;
            o.x = f2bf(fmaxf(acc0[hh][m][n][0] + bv.x, 0.f));
            o.y = f2bf(fmaxf(acc0[hh][m][n][1] + bv.y, 0.f));
            o.z = f2bf(fmaxf(acc0[hh][m][n][2] + bv.z, 0.f));
            o.w = f2bf(fmaxf(acc0[hh][m][n][3] + bv.w, 0.f));
            const int u = ch >> 3, su = u ^ (s & 7);
            *(ushort4*)&h0s[s * 512 + su * 8 + (ch & 7)] = o;
        }
    }
    __syncthreads();

    // P1: h1 = relu(h0 @ bw1^T + bb1), K=512
    f32x4 acc1[2][4] = {};
    for (int kt = 0; kt < 512; kt += 32) {
#pragma unroll
        for (int i = 0; i < 4; ++i) {
            const int idx = i * 256 + t;
            const int r = idx >> 2, u = idx & 3, us = u ^ ((r >> 1) & 3);
            stage16(bw1c + (size_t)r * 512 + kt + us * 8, &Wst[idx * 8]);
        }
        __syncthreads();
        short8v a[2], b[4];
#pragma unroll
        for (int m = 0; m < 2; ++m) {
            const int s = m * 16 + fr;
            const int u = (kt >> 3) + j16, su = u ^ (s & 7);
            a[m] = *(const short8v*)&h0s[s * 512 + su * 8];
        }
#pragma unroll
        for (int n = 0; n < 4; ++n) {
            const int lr = w * 64 + n * 16 + fr;
            b[n] = *(const short8v*)&Wst[lr * 32 + (j16 ^ ((lr >> 1) & 3)) * 8];
        }
        __builtin_amdgcn_s_setprio(1);
#pragma unroll
        for (int m = 0; m < 2; ++m)
#pragma unroll
            for (int n = 0; n < 4; ++n)
                acc1[m][n] = __builtin_amdgcn_mfma_f32_16x16x32_bf16(b[n], a[m], acc1[m][n], 0, 0, 0);
        __builtin_amdgcn_s_setprio(0);
        __syncthreads();
    }
#pragma unroll
    for (int n = 0; n < 4; ++n) {
        const int ch = w * 64 + n * 16 + j16 * 4;
        const float4 bv = *(const float4*)&bb1[ch];
#pragma unroll
        for (int m = 0; m < 2; ++m) {
            const int s = m * 16 + fr;
            ushort4 o;
            o.x = f2bf(fmaxf(acc1[m][n][0] + bv.x, 0.f));
            o.y = f2bf(fmaxf(acc1[m][n][1] + bv.y, 0.f));
            o.z = f2bf(fmaxf(acc1[m][n][2] + bv.z, 0.f));
            o.w = f2bf(fmaxf(acc1[m][n][3] + bv.w, 0.f));
            const int u = ch >> 3, su = u ^ (s & 7);
            *(ushort4*)&h1s[s * 256 + su * 8 + (ch & 7)] = o;
        }
    }
    __syncthreads();

    // P2: x_bot = relu(h1 @ bw2^T + bb2) -> Rb[B][64]
    f32x4 acc2[2] = {};
    for (int kt = 0; kt < 256; kt += 32) {
        {
            const int r = t >> 2, u = t & 3, us = u ^ ((r >> 1) & 3);
            stage16(bw2c + (size_t)r * 256 + kt + us * 8, &Wst[t * 8]);
        }
        __syncthreads();
        short8v a[2], b;
#pragma unroll
        for (int m = 0; m < 2; ++m) {
            const int s = m * 16 + fr;
            const int u = (kt >> 3) + j16, su = u ^ (s & 7);
            a[m] = *(const short8v*)&h1s[s * 256 + su * 8];
        }
        {
            const int lr = w * 16 + fr;
            b = *(const short8v*)&Wst[lr * 32 + (j16 ^ ((lr >> 1) & 3)) * 8];
        }
#pragma unroll
        for (int m = 0; m < 2; ++m)
            acc2[m] = __builtin_amdgcn_mfma_f32_16x16x32_bf16(b, a[m], acc2[m], 0, 0, 0);
        __syncthreads();
    }
    {
        const int ch = w * 16 + j16 * 4;
        const float4 bv = *(const float4*)&bb2[ch];
#pragma unroll
        for (int m = 0; m < 2; ++m) {
            const int s = m * 16 + fr;
            ushort4 o;
            o.x = f2bf(fmaxf(acc2[m][0] + bv.x, 0.f));
            o.y = f2bf(fmaxf(acc2[m][1] + bv.y, 0.f));
            o.z = f2bf(fmaxf(acc2[m][2] + bv.z, 0.f));
            o.w = f2bf(fmaxf(acc2[m][3] + bv.w, 0.f));
            *(ushort4*)&Rb[(size_t)(bBase + s) * 64 + ch] = o;
        }
    }
}

// ---------------------------------------------------------------------------
// Fused gather + interaction + top MLP. 32 samples/block, 4 waves,
// LDS 79.6 KB -> 2 blocks/CU (gather of one block overlaps MFMA of the other).
// Z = T.T^T per sample via 32x32x16 MFMA with identical A/B operands.
// ---------------------------------------------------------------------------
__global__ __launch_bounds__(256, 2) void topint_k(
    const float* __restrict__ emb, const int* __restrict__ indices,
    const ushort* __restrict__ Rb, const ushort* __restrict__ tw0p,
    const float* __restrict__ tb0, const ushort* __restrict__ tw1c,
    const float* __restrict__ tb1, const float* __restrict__ tw2,
    const float* __restrict__ tb2, float* __restrict__ out)
{
    __shared__ __align__(16) ushort Rt[32 * 424];    // 26.5 KB, stride 53 16B-units
    __shared__ __align__(16) ushort th0s[32 * 512];  // 32 KB
    __shared__ __align__(16) ushort Wst[256 * 32];   // 16 KB staging
    __shared__ __align__(16) int scratch[832];       // sidx[26][32]; reused as red[]
    const int t = threadIdx.x;
    const int lane = t & 63, w = t >> 6;
    const int fr = lane & 15, j16 = lane >> 4;
    const int bBase = blockIdx.x * 32;

    // P0: x_bot -> Rt[:, 0:64]; zero col 415; load indices
    {
        const int r = t >> 3, u = t & 7;
        short8v v = *(const short8v*)&Rb[(size_t)(bBase + r) * 64 + u * 8];
        *(short8v*)&Rt[r * 424 + u * 8] = v;
    }
    if (t < 32) Rt[t * 424 + 415] = 0;
    for (int e = t; e < 832; e += 256)
        scratch[e] = indices[(size_t)(e >> 5) * B_SZ + bBase + (e & 31)];
    __syncthreads();

    // P1: per wave-sample, Z = T.T^T via 4x mfma_32x32x16 (A == B == T fragments).
    // T row 0 = x_bot (bf16 from Rt); rows 1..26 = emb rows (fp32 -> bf16 in regs).
    {
        const int r32 = lane & 31, half = lane >> 5;
        for (int it = 0; it < 8; ++it) {
            const int s = it * 4 + w;
            short8v tf[4];
            if (r32 == 0) {
#pragma unroll
                for (int kq = 0; kq < 4; ++kq)
                    tf[kq] = *(const short8v*)&Rt[s * 424 + kq * 16 + half * 8];
            } else if (r32 <= 26) {
                const int idxv = scratch[(r32 - 1) * 32 + s];
                const float* rp = emb + ((size_t)(r32 - 1) * NROWS + (size_t)idxv) * 64 + half * 8;
#pragma unroll
                for (int kq = 0; kq < 4; ++kq) {
                    const float4 x = *(const float4*)&rp[kq * 16];
                    const float4 y = *(const float4*)&rp[kq * 16 + 4];
                    short8v v;
                    v[0] = (short)f2bf(x.x); v[1] = (short)f2bf(x.y);
                    v[2] = (short)f2bf(x.z); v[3] = (short)f2bf(x.w);
                    v[4] = (short)f2bf(y.x); v[5] = (short)f2bf(y.y);
                    v[6] = (short)f2bf(y.z); v[7] = (short)f2bf(y.w);
                    tf[kq] = v;
                }
            } else {
#pragma unroll
                for (int kq = 0; kq < 4; ++kq) tf[kq] = (short8v)0;
            }
            f32x16 c = {};
#pragma unroll
            for (int kq = 0; kq < 4; ++kq)
                c = __builtin_amdgcn_mfma_f32_32x32x16_bf16(tf[kq], tf[kq], c, 0, 0, 0);
            // extract strict lower triangle: row=(reg&3)+8*(reg>>2)+4*half, col=r32
#pragma unroll
            for (int reg = 0; reg < 16; ++reg) {
                const int r = (reg & 3) + 8 * (reg >> 2) + 4 * half;
                if (r < 27 && r32 < r)
                    Rt[s * 424 + 64 + (r * (r - 1)) / 2 + r32] = f2bf(c[reg]);
            }
        }
    }
    __syncthreads();

    // phase A: th0 = relu(R @ tw0^T + tb0), K=416, 2 channel halves of 256
    f32x4 accA[2][2][4] = {};
    for (int kt = 0; kt < 416; kt += 32) {
        short8v a[2];
#pragma unroll
        for (int m = 0; m < 2; ++m) {
            const int s = m * 16 + fr;
            a[m] = *(const short8v*)&Rt[s * 424 + ((kt >> 3) + j16) * 8];
        }
#pragma unroll
        for (int hh = 0; hh < 2; ++hh) {
#pragma unroll
            for (int i = 0; i < 4; ++i) {
                const int idx = i * 256 + t;
                const int r = idx >> 2, u = idx & 3, us = u ^ ((r >> 1) & 3);
                stage16(tw0p + (size_t)(hh * 256 + r) * 416 + kt + us * 8, &Wst[idx * 8]);
            }
            __syncthreads();
            short8v b[4];
#pragma unroll
            for (int n = 0; n < 4; ++n) {
                const int lr = w * 64 + n * 16 + fr;
                b[n] = *(const short8v*)&Wst[lr * 32 + (j16 ^ ((lr >> 1) & 3)) * 8];
            }
            __builtin_amdgcn_s_setprio(1);
#pragma unroll
            for (int m = 0; m < 2; ++m)
#pragma unroll
                for (int n = 0; n < 4; ++n)
                    accA[hh][m][n] = __builtin_amdgcn_mfma_f32_16x16x32_bf16(b[n], a[m], accA[hh][m][n], 0, 0, 0);
            __builtin_amdgcn_s_setprio(0);
            __syncthreads();
        }
    }
#pragma unroll
    for (int hh = 0; hh < 2; ++hh)
#pragma unroll
    for (int n = 0; n < 4; ++n) {
        const int ch = hh * 256 + w * 64 + n * 16 + j16 * 4;
        const float4 bv = *(const float4*)&tb0[ch];
#pragma unroll
        for (int m = 0; m < 2; ++m) {
            const int s = m * 16 + fr;
            ushort4 o;
            o.x = f2bf(fmaxf(accA[hh][m][n][0] + bv.x, 0.f));
            o.y = f2bf(fmaxf(accA[hh][m][n][1] + bv.y, 0.f));
            o.z = f2bf(fmaxf(accA[hh][m][n][2] + bv.z, 0.f));
            o.w = f2bf(fmaxf(accA[hh][m][n][3] + bv.w, 0.f));
            const int u = ch >> 3, su = u ^ (s & 7);
            *(ushort4*)&th0s[s * 512 + su * 8 + (ch & 7)] = o;
        }
    }
    __syncthreads();

    // phase B: th1 = relu(th0 @ tw1^T + tb1), K=512
    f32x4 acc2[2][4] = {};
    for (int kt = 0; kt < 512; kt += 32) {
#pragma unroll
        for (int i = 0; i < 4; ++i) {
            const int idx = i * 256 + t;
            const int r = idx >> 2, u = idx & 3, us = u ^ ((r >> 1) & 3);
            stage16(tw1c + (size_t)r * 512 + kt + us * 8, &Wst[idx * 8]);
        }
        __syncthreads();
        short8v a[2], b[4];
#pragma unroll
        for (int m = 0; m < 2; ++m) {
            const int s = m * 16 + fr;
            const int u = (kt >> 3) + j16, su = u ^ (s & 7);
            a[m] = *(const short8v*)&th0s[s * 512 + su * 8];
        }
#pragma unroll
        for (int n = 0; n < 4; ++n) {
            const int lr = w * 64 + n * 16 + fr;
            b[n] = *(const short8v*)&Wst[lr * 32 + (j16 ^ ((lr >> 1) & 3)) * 8];
        }
        __builtin_amdgcn_s_setprio(1);
#pragma unroll
        for (int m = 0; m < 2; ++m)
#pragma unroll
            for (int n = 0; n < 4; ++n)
                acc2[m][n] = __builtin_amdgcn_mfma_f32_16x16x32_bf16(b[n], a[m], acc2[m][n], 0, 0, 0);
        __builtin_amdgcn_s_setprio(0);
        __syncthreads();
    }

    // phase C: out = sigmoid( relu(th1) . tw2 + tb2 )
    float* red = (float*)scratch;
    float part[2] = {0.f, 0.f};
#pragma unroll
    for (int n = 0; n < 4; ++n) {
        const int ch = w * 64 + n * 16 + j16 * 4;
        const float4 bv = *(const float4*)&tb1[ch];
        const float4 wv = *(const float4*)&tw2[ch];
#pragma unroll
        for (int m = 0; m < 2; ++m) {
            part[m] += fmaxf(acc2[m][n][0] + bv.x, 0.f) * wv.x
                     + fmaxf(acc2[m][n][1] + bv.y, 0.f) * wv.y
                     + fmaxf(acc2[m][n][2] + bv.z, 0.f) * wv.z
                     + fmaxf(acc2[m][n][3] + bv.w, 0.f) * wv.w;
        }
    }
#pragma unroll
    for (int m = 0; m < 2; ++m) {
        float v = part[m];
        v += __shfl_xor(v, 16, 64);
        v += __shfl_xor(v, 32, 64);
        if (lane < 16) red[w * 32 + m * 16 + fr] = v;
    }
    __syncthreads();
    if (t < 32) {
        const float sm = red[t] + red[32 + t] + red[64 + t] + red[96 + t];
        out[bBase + t] = 1.f / (1.f + expf(-(sm + tb2[0])));
    }
}

extern "C" void kernel_launch(void* const* d_in, const int* in_sizes, int n_in,
                              void* d_out, int out_size, void* d_ws, size_t ws_size,
                              hipStream_t stream)
{
    (void)in_sizes; (void)n_in; (void)out_size; (void)ws_size;
    const float* dense_x = (const float*)d_in[0];
    const int*   indices = (const int*)d_in[1];
    const float* emb     = (const float*)d_in[2];
    const float* bw0 = (const float*)d_in[3];
    const float* bb0 = (const float*)d_in[4];
    const float* bw1 = (const float*)d_in[5];
    const float* bb1 = (const float*)d_in[6];
    const float* bw2 = (const float*)d_in[7];
    const float* bb2 = (const float*)d_in[8];
    const float* tw0 = (const float*)d_in[9];
    const float* tb0 = (const float*)d_in[10];
    const float* tw1 = (const float*)d_in[11];
    const float* tb1 = (const float*)d_in[12];
    const float* tw2 = (const float*)d_in[13];
    const float* tb2 = (const float*)d_in[14];
    float* out = (float*)d_out;

    ushort* ws16      = (ushort*)d_ws;
    ushort* dense_pad = ws16;                              // B x 32
    ushort* Rb        = dense_pad + (size_t)B_SZ * 32;     // B x 64 (x_bot)
    ushort* bw0p      = Rb + (size_t)B_SZ * 64;            // 512 x 32
    ushort* tw0p      = bw0p + 512 * 32;                   // 512 x 416
    ushort* bw1c      = tw0p + 512 * 416;                  // 256 x 512
    ushort* bw2c      = bw1c + 256 * 512;                  // 64 x 256
    ushort* tw1c      = bw2c + 64 * 256;                   // 256 x 512

    conv_all_k<<<dim3(6080), dim3(256), 0, stream>>>(
        dense_x, bw0, tw0, bw1, bw2, tw1,
        dense_pad, bw0p, tw0p, bw1c, bw2c, tw1c);

    bot012_k<<<dim3(B_SZ / 32), dim3(256), 0, stream>>>(
        dense_pad, bw0p, bb0, bw1c, bb1, bw2c, bb2, Rb);

    topint_k<<<dim3(B_SZ / 32), dim3(256), 0, stream>>>(
        emb, indices, Rb, tw0p, tb0, tw1c, tb1, tw2, tb2, out);
}